// Round 1
// 413.702 us; speedup vs baseline: 1.0246x; 1.0246x over previous
//
#include <hip/hip_runtime.h>
#include <cstdint>

// ---------------------------------------------------------------------------
// W8A8 linear: y = int8_gemm(quant(x), W^T) * alpha
//   x: fp32 [M=8192, K=4096], W int32-materialized -> packed int8 in d_ws.
//
// GEMM v2: 256x256 tile, BK=64 bytes, 512 threads (8 waves, 2Mx4N),
// per-wave 128x64 as 4x2 of v_mfma_i32_32x32x32_i8.
//  - TRIPLE-buffered LDS (3 x 32 KiB = 96 KiB): while computing tile t,
//    tile t+1 is resident and tile t+2 is in flight -> boundary wait is
//    s_waitcnt vmcnt(4) (counted, never 0 in steady state).
//  - Phase-split K-loop (2 phases/K-tile = one per 32-elem k-step), raw
//    s_barrier (NOT __syncthreads -> no vmcnt(0) drain), s_setprio(1)
//    around each 8-MFMA cluster.
//  - LDS swizzle fixed: 64-B rows = 16 banks, so position p of row r holds
//    kgroup p ^ ((r>>1)&3) (old r&3 variant left 2-way conflicts -> 5e7
//    SQ_LDS_BANK_CONFLICT). 8 consecutive rows now cover all 8 bank-quads.
//    global_load_lds dest stays linear; the swizzle is applied to the
//    global SOURCE address and to the ds_read address (both-sides rule).
// ---------------------------------------------------------------------------

typedef int v4i  __attribute__((ext_vector_type(4)));
typedef int v16i __attribute__((ext_vector_type(16)));

#define BM 256
#define BN 256
#define BKB 64                    // K bytes (= i8 elements) per K-tile
#define LDS_TILE (BM * BKB)       // 16 KiB per matrix tile
#define LDS_BUF  (2 * LDS_TILE)   // 32 KiB per (A,B) buffer
#define NBUF 3                    // triple buffer -> 96 KiB LDS

// ---- fused prologue: quant x + pack w, grid-stride (2048 blocks; the old
// 49152-block launch was a dispatch-overhead suspect) ------------------------
__global__ void prep_kernel(const float* __restrict__ x,
                            signed char* __restrict__ q,
                            const int* __restrict__ w32,
                            signed char* __restrict__ w8,
                            const float* __restrict__ inscale_ptr,
                            int nq, int total) {
    const float s = *inscale_ptr;
    const int stride = gridDim.x * blockDim.x;
    for (int i = blockIdx.x * blockDim.x + threadIdx.x; i < total; i += stride) {
        if (i < nq) {
            float4 f = ((const float4*)x)[i];
            union { signed char c[4]; int v; } u;
            float vals[4] = {f.x, f.y, f.z, f.w};
#pragma unroll
            for (int e = 0; e < 4; ++e) {
                // IEEE divide + rint (half-even) matches np.round(xf/inscale)
                float r = rintf(vals[e] / s);
                r = fminf(fmaxf(r, -128.0f), 127.0f);
                u.c[e] = (signed char)(int)r;
            }
            ((int*)q)[i] = u.v;
        } else {
            const int j = i - nq;
            int4 w = ((const int4*)w32)[j];
            union { signed char c[4]; int v; } u;
            u.c[0] = (signed char)w.x;
            u.c[1] = (signed char)w.y;
            u.c[2] = (signed char)w.z;
            u.c[3] = (signed char)w.w;
            ((int*)w8)[j] = u.v;
        }
    }
}

// ---- async global->LDS, 16B per lane (dest = wave-uniform base + lane*16) --
__device__ __forceinline__ void async16(void* lds, const void* g) {
    __builtin_amdgcn_global_load_lds(
        (const __attribute__((address_space(1))) void*)g,
        (__attribute__((address_space(3))) void*)lds,
        16, 0, 0);
}

// ---- int8 GEMM --------------------------------------------------------------
__global__ __launch_bounds__(512, 2)
void w8a8_gemm(const signed char* __restrict__ A,   // [M,K] quantized acts
               const signed char* __restrict__ Bw,  // [N,K] packed weights
               float* __restrict__ C,               // [M,N] fp32 out
               const float* __restrict__ alpha_ptr,
               int M, int N, int K) {
    __shared__ signed char lds[NBUF * LDS_BUF];     // 96 KiB

    const int t    = threadIdx.x;
    const int lane = t & 63;
    const int wave = t >> 6;
    const int wm   = (wave >> 2) * 128;   // 2 wave-rows
    const int wn   = (wave & 3) * 64;     // 4 wave-cols

    // XCD-aware bijective block swizzle (grid = 512, multiple of 8)
    const int nbx   = N / BN;
    const int swz   = ((int)blockIdx.x & 7) * ((int)gridDim.x >> 3)
                    + ((int)blockIdx.x >> 3);
    const int tileM = (swz / nbx) * BM;
    const int tileN = (swz % nbx) * BN;

    // ---- staging source addresses (swizzle-aware) ----
    // Thread t stages chunk (row = t>>2, pos = t&3) of each 128-row half.
    // LDS dest linear; stored pos p of row r holds global kgroup p^((r>>1)&3).
    // (row+128 has the same (row>>1)&3 -> same sg for both halves.)
    const int srow = t >> 2;
    const int sg   = (t & 3) ^ ((t >> 3) & 3);
    const size_t aOff0 = (size_t)(tileM + srow)       * K + sg * 16;
    const size_t aOff1 = (size_t)(tileM + 128 + srow) * K + sg * 16;
    const size_t bOff0 = (size_t)(tileN + srow)       * K + sg * 16;
    const size_t bOff1 = (size_t)(tileN + 128 + srow) * K + sg * 16;
    const int ldst = t * 16;

    auto stageA = [&](int kt, int buf) {
        const size_t ko = (size_t)kt * BKB;
        signed char* d = &lds[buf * LDS_BUF];
        async16(d + ldst,        A + aOff0 + ko);
        async16(d + 8192 + ldst, A + aOff1 + ko);
    };
    auto stageB = [&](int kt, int buf) {
        const size_t ko = (size_t)kt * BKB;
        signed char* d = &lds[buf * LDS_BUF + LDS_TILE];
        async16(d + ldst,        Bw + bOff0 + ko);
        async16(d + 8192 + ldst, Bw + bOff1 + ko);
    };

    // ---- fragment LDS addressing (32x32x32 i8) ----
    // lane reads row = (group base)+ (lane&31), k bytes [khalf*16,+16) of the
    // 32-elem k-step; swizzled position = kgroup ^ ((row>>1)&3).
    // (row>>1)&3 == (mrow>>1)&3 for all 32-aligned group bases.
    const int mrow  = lane & 31;
    const int khalf = lane >> 5;
    const int fswz  = (mrow >> 1) & 3;
    const int offS0 = ((0 + khalf) ^ fswz) * 16;   // k-step 0: kgroups 0/1
    const int offS1 = ((2 + khalf) ^ fswz) * 16;   // k-step 1: kgroups 2/3
    int arow[4], brow[2];
#pragma unroll
    for (int im = 0; im < 4; ++im) arow[im] = (wm + im * 32 + mrow) * BKB;
#pragma unroll
    for (int jn = 0; jn < 2; ++jn) brow[jn] = LDS_TILE + (wn + jn * 32 + mrow) * BKB;

    v16i acc[4][2] = {};   // 128 VGPRs

    auto phase = [&](const signed char* cb, int offp) {
        v4i a[4], b[2];
#pragma unroll
        for (int im = 0; im < 4; ++im)
            a[im] = *(const v4i*)(cb + arow[im] + offp);
#pragma unroll
        for (int jn = 0; jn < 2; ++jn)
            b[jn] = *(const v4i*)(cb + brow[jn] + offp);
        asm volatile("s_barrier" ::: "memory");    // phase-entry lockstep
        __builtin_amdgcn_s_setprio(1);
#pragma unroll
        for (int im = 0; im < 4; ++im)
#pragma unroll
            for (int jn = 0; jn < 2; ++jn)
                acc[im][jn] = __builtin_amdgcn_mfma_i32_32x32x32_i8(
                    a[im], b[jn], acc[im][jn], 0, 0, 0);
        __builtin_amdgcn_s_setprio(0);
    };

    // ---- prologue: stage tiles 0 and 1 (8 loads), wait only tile 0 ----
    stageA(0, 0); stageB(0, 0);
    stageA(1, 1); stageB(1, 1);
    asm volatile("s_waitcnt vmcnt(4)" ::: "memory");   // tile 0 landed
    asm volatile("s_barrier" ::: "memory");

    const int NT = K / BKB;   // 64 K-tiles
    int bc = 0, sb = 2;
#pragma unroll 1
    for (int kt = 0; kt < NT; ++kt) {
        const bool doStage = (kt + 2) < NT;
        const signed char* cb = &lds[bc * LDS_BUF];

        // ---- phase 0 (k-step 0): stage A-half of tile kt+2 ----
        if (doStage) stageA(kt + 2, sb);
        phase(cb, offS0);
        asm volatile("s_barrier" ::: "memory");

        // ---- phase 1 (k-step 1): stage B-half of tile kt+2 ----
        if (doStage) stageB(kt + 2, sb);
        phase(cb, offS1);

        // boundary: ensure tile kt+1 resident; leave tile kt+2's 4 loads
        // in flight across the barrier (counted vmcnt, AITER-style).
        if (doStage) asm volatile("s_waitcnt vmcnt(4)" ::: "memory");
        else         asm volatile("s_waitcnt vmcnt(0)" ::: "memory");
        asm volatile("s_barrier" ::: "memory");

        bc = (bc == NBUF - 1) ? 0 : bc + 1;
        sb = (sb == NBUF - 1) ? 0 : sb + 1;
    }

    // ---- epilogue: C/D layout col=lane&31, row=(reg&3)+8*(reg>>2)+4*khalf --
    const float alpha = *alpha_ptr;
    const int ccol  = lane & 31;
    const int rquad = khalf * 4;
#pragma unroll
    for (int im = 0; im < 4; ++im) {
#pragma unroll
        for (int jn = 0; jn < 2; ++jn) {
            const int baseRow = tileM + wm + im * 32;
            const int col     = tileN + wn + jn * 32 + ccol;
#pragma unroll
            for (int reg = 0; reg < 16; ++reg) {
                const int row = baseRow + (reg & 3) + 8 * (reg >> 2) + rquad;
                C[(size_t)row * N + col] = (float)acc[im][jn][reg] * alpha;
            }
        }
    }
}

extern "C" void kernel_launch(void* const* d_in, const int* in_sizes, int n_in,
                              void* d_out, int out_size, void* d_ws, size_t ws_size,
                              hipStream_t stream) {
    const float* x       = (const float*)d_in[0];
    const int*   w32     = (const int*)d_in[1];
    const float* alpha   = (const float*)d_in[2];
    const float* inscale = (const float*)d_in[3];
    float*       out     = (float*)d_out;

    const int K = 4096;
    const int N = 4096;
    const int M = in_sizes[0] / K;    // 8192

    signed char* q  = (signed char*)d_ws;                     // 32 MiB
    signed char* w8 = (signed char*)d_ws + (size_t)M * K;     // +16 MiB

    const int nq    = (M * K) / 4;    // float4 units
    const int total = nq + (N * K) / 4;
    prep_kernel<<<2048, 256, 0, stream>>>(x, q, w32, w8, inscale, nq, total);

    dim3 grid((M / BM) * (N / BN));   // 32*16 = 512 blocks, 1 per CU
    w8a8_gemm<<<grid, 512, 0, stream>>>(q, w8, out, alpha, M, N, K);
}

// Round 2
// 406.321 us; speedup vs baseline: 1.0432x; 1.0182x over previous
//
#include <hip/hip_runtime.h>
#include <cstdint>

// ---------------------------------------------------------------------------
// W8A8 linear: y = int8_gemm(quant(x), W^T) * alpha
//   x: fp32 [M=8192, K=4096], W int32-materialized -> packed int8 in d_ws.
//
// GEMM v3: 256x256 tile, BK=64 bytes, 512 threads (8 waves, 2Mx4N),
// per-wave 128x64 as 4x2 of v_mfma_i32_32x32x32_i8.
//
//  Round-1 post-mortem: 4 barriers/K-tile (phase-entry lockstep) kept
//  MfmaUtil pinned at 35% -- the matrix pipe idled in every read/converge
//  window. v3 keeps ONLY the correctness barrier:
//    per K-tile: 12x ds_read_b128 -> stage kt+2 (4x global_load_lds)
//                -> setprio(1) + 16 MFMA + setprio(0)
//                -> s_waitcnt vmcnt(4) -> ONE s_barrier.
//  Triple buffer makes this sound: reads target buf kt%3, stages target
//  (kt+2)%3, and the boundary barrier stops any wave entering kt+1 (which
//  stages into kt%3) before all waves finished kt's reads. vmcnt(4) at the
//  boundary retires exactly the 4 oldest loads (tile kt+1), leaving tile
//  kt+2's 4 loads in flight across the barrier (counted, never 0).
//
//  LDS swizzle (unchanged, verified): 64-B rows = 16 banks; position p of
//  row r holds kgroup p ^ ((r>>1)&3); 8 consecutive rows cover all 8
//  bank-quads. global_load_lds dest linear; swizzle applied to the global
//  SOURCE address and the ds_read address (both-sides rule).
// ---------------------------------------------------------------------------

typedef int v4i  __attribute__((ext_vector_type(4)));
typedef int v16i __attribute__((ext_vector_type(16)));

#define BM 256
#define BN 256
#define BKB 64                    // K bytes (= i8 elements) per K-tile
#define LDS_TILE (BM * BKB)       // 16 KiB per matrix tile
#define LDS_BUF  (2 * LDS_TILE)   // 32 KiB per (A,B) buffer
#define NBUF 3                    // triple buffer -> 96 KiB LDS

// ---- fused prologue: quant x + pack w, grid-stride -------------------------
__global__ void prep_kernel(const float* __restrict__ x,
                            signed char* __restrict__ q,
                            const int* __restrict__ w32,
                            signed char* __restrict__ w8,
                            const float* __restrict__ inscale_ptr,
                            int nq, int total) {
    const float s = *inscale_ptr;
    const int stride = gridDim.x * blockDim.x;
    for (int i = blockIdx.x * blockDim.x + threadIdx.x; i < total; i += stride) {
        if (i < nq) {
            float4 f = ((const float4*)x)[i];
            union { signed char c[4]; int v; } u;
            float vals[4] = {f.x, f.y, f.z, f.w};
#pragma unroll
            for (int e = 0; e < 4; ++e) {
                // IEEE divide + rint (half-even) matches np.round(xf/inscale)
                float r = rintf(vals[e] / s);
                r = fminf(fmaxf(r, -128.0f), 127.0f);
                u.c[e] = (signed char)(int)r;
            }
            ((int*)q)[i] = u.v;
        } else {
            const int j = i - nq;
            int4 w = ((const int4*)w32)[j];
            union { signed char c[4]; int v; } u;
            u.c[0] = (signed char)w.x;
            u.c[1] = (signed char)w.y;
            u.c[2] = (signed char)w.z;
            u.c[3] = (signed char)w.w;
            ((int*)w8)[j] = u.v;
        }
    }
}

// ---- async global->LDS, 16B per lane (dest = wave-uniform base + lane*16) --
__device__ __forceinline__ void async16(void* lds, const void* g) {
    __builtin_amdgcn_global_load_lds(
        (const __attribute__((address_space(1))) void*)g,
        (__attribute__((address_space(3))) void*)lds,
        16, 0, 0);
}

// ---- int8 GEMM --------------------------------------------------------------
__global__ __launch_bounds__(512, 2)
void w8a8_gemm(const signed char* __restrict__ A,   // [M,K] quantized acts
               const signed char* __restrict__ Bw,  // [N,K] packed weights
               float* __restrict__ C,               // [M,N] fp32 out
               const float* __restrict__ alpha_ptr,
               int M, int N, int K) {
    __shared__ signed char lds[NBUF * LDS_BUF];     // 96 KiB

    const int t    = threadIdx.x;
    const int lane = t & 63;
    const int wave = t >> 6;
    const int wm   = (wave >> 2) * 128;   // 2 wave-rows
    const int wn   = (wave & 3) * 64;     // 4 wave-cols

    // XCD-aware bijective block swizzle (grid = 512, multiple of 8)
    const int nbx   = N / BN;
    const int swz   = ((int)blockIdx.x & 7) * ((int)gridDim.x >> 3)
                    + ((int)blockIdx.x >> 3);
    const int tileM = (swz / nbx) * BM;
    const int tileN = (swz % nbx) * BN;

    // ---- staging source addresses (swizzle-aware) ----
    // Thread t stages chunk (row = t>>2, pos = t&3) of each 128-row half.
    // LDS dest linear; stored pos p of row r holds global kgroup p^((r>>1)&3).
    const int srow = t >> 2;
    const int sg   = (t & 3) ^ ((t >> 3) & 3);
    const size_t aOff0 = (size_t)(tileM + srow)       * K + sg * 16;
    const size_t aOff1 = (size_t)(tileM + 128 + srow) * K + sg * 16;
    const size_t bOff0 = (size_t)(tileN + srow)       * K + sg * 16;
    const size_t bOff1 = (size_t)(tileN + 128 + srow) * K + sg * 16;
    const int ldst = t * 16;

    auto stageA = [&](int kt, int buf) {
        const size_t ko = (size_t)kt * BKB;
        signed char* d = &lds[buf * LDS_BUF];
        async16(d + ldst,        A + aOff0 + ko);
        async16(d + 8192 + ldst, A + aOff1 + ko);
    };
    auto stageB = [&](int kt, int buf) {
        const size_t ko = (size_t)kt * BKB;
        signed char* d = &lds[buf * LDS_BUF + LDS_TILE];
        async16(d + ldst,        Bw + bOff0 + ko);
        async16(d + 8192 + ldst, Bw + bOff1 + ko);
    };

    // ---- fragment LDS addressing (32x32x32 i8) ----
    // lane reads row = base + (lane&31), bytes [khalf*16,+16) of k-step s;
    // kgroup = 2s+khalf, swizzled position = kgroup ^ ((row>>1)&3).
    const int mrow  = lane & 31;
    const int khalf = lane >> 5;
    const int fswz  = (mrow >> 1) & 3;
    const int offS[2] = { ((0 + khalf) ^ fswz) * 16,     // k-step 0
                          ((2 + khalf) ^ fswz) * 16 };   // k-step 1
    int arow[4], brow[2];
#pragma unroll
    for (int im = 0; im < 4; ++im) arow[im] = (wm + im * 32 + mrow) * BKB;
#pragma unroll
    for (int jn = 0; jn < 2; ++jn) brow[jn] = LDS_TILE + (wn + jn * 32 + mrow) * BKB;

    v16i acc[4][2] = {};   // 128 accumulator regs

    // ---- prologue: stage tiles 0 and 1 (8 loads), wait only tile 0 ----
    stageA(0, 0); stageB(0, 0);
    stageA(1, 1); stageB(1, 1);
    asm volatile("s_waitcnt vmcnt(4)" ::: "memory");   // tile 0 landed
    __builtin_amdgcn_s_barrier();

    const int NT = K / BKB;   // 64 K-tiles
    int bc = 0, sb = 2;
#pragma unroll 1
    for (int kt = 0; kt < NT; ++kt) {
        const bool doStage = (kt + 2) < NT;
        const signed char* cb = &lds[bc * LDS_BUF];

        // ---- all 12 fragment reads up front (latency hides under the
        //      stage issue + the other wave's MFMA cluster on this SIMD) ----
        v4i a[2][4], b[2][2];
#pragma unroll
        for (int s = 0; s < 2; ++s) {
            const int offp = offS[s];
#pragma unroll
            for (int im = 0; im < 4; ++im)
                a[s][im] = *(const v4i*)(cb + arow[im] + offp);
#pragma unroll
            for (int jn = 0; jn < 2; ++jn)
                b[s][jn] = *(const v4i*)(cb + brow[jn] + offp);
        }

        // ---- issue next-next tile's 4 staging loads ----
        if (doStage) { stageA(kt + 2, sb); stageB(kt + 2, sb); }

        // ---- 16-MFMA cluster; compiler inserts split lgkmcnt waits ----
        __builtin_amdgcn_s_setprio(1);
#pragma unroll
        for (int s = 0; s < 2; ++s)
#pragma unroll
            for (int im = 0; im < 4; ++im)
#pragma unroll
                for (int jn = 0; jn < 2; ++jn)
                    acc[im][jn] = __builtin_amdgcn_mfma_i32_32x32x32_i8(
                        a[s][im], b[s][jn], acc[im][jn], 0, 0, 0);
        __builtin_amdgcn_s_setprio(0);

        // ---- boundary: tile kt+1 resident; tile kt+2's 4 loads stay in
        //      flight across the barrier (counted vmcnt, never 0) ----
        if (doStage) asm volatile("s_waitcnt vmcnt(4)" ::: "memory");
        else         asm volatile("s_waitcnt vmcnt(0)" ::: "memory");
        __builtin_amdgcn_s_barrier();

        bc = (bc == NBUF - 1) ? 0 : bc + 1;
        sb = (sb == NBUF - 1) ? 0 : sb + 1;
    }

    // ---- epilogue: C/D layout col=lane&31, row=(reg&3)+8*(reg>>2)+4*khalf --
    const float alpha = *alpha_ptr;
    const int ccol  = lane & 31;
    const int rquad = khalf * 4;
#pragma unroll
    for (int im = 0; im < 4; ++im) {
#pragma unroll
        for (int jn = 0; jn < 2; ++jn) {
            const int baseRow = tileM + wm + im * 32;
            const int col     = tileN + wn + jn * 32 + ccol;
#pragma unroll
            for (int reg = 0; reg < 16; ++reg) {
                const int row = baseRow + (reg & 3) + 8 * (reg >> 2) + rquad;
                C[(size_t)row * N + col] = (float)acc[im][jn][reg] * alpha;
            }
        }
    }
}

extern "C" void kernel_launch(void* const* d_in, const int* in_sizes, int n_in,
                              void* d_out, int out_size, void* d_ws, size_t ws_size,
                              hipStream_t stream) {
    const float* x       = (const float*)d_in[0];
    const int*   w32     = (const int*)d_in[1];
    const float* alpha   = (const float*)d_in[2];
    const float* inscale = (const float*)d_in[3];
    float*       out     = (float*)d_out;

    const int K = 4096;
    const int N = 4096;
    const int M = in_sizes[0] / K;    // 8192

    signed char* q  = (signed char*)d_ws;                     // 32 MiB
    signed char* w8 = (signed char*)d_ws + (size_t)M * K;     // +16 MiB

    const int nq    = (M * K) / 4;    // float4 units
    const int total = nq + (N * K) / 4;
    prep_kernel<<<2048, 256, 0, stream>>>(x, q, w32, w8, inscale, nq, total);

    dim3 grid((M / BM) * (N / BN));   // 32*16 = 512 blocks, 1 per CU
    w8a8_gemm<<<grid, 512, 0, stream>>>(q, w8, out, alpha, M, N, K);
}